// Round 5
// baseline (1444.359 us; speedup 1.0000x reference)
//
#include <hip/hip_runtime.h>
#include <hip/hip_bf16.h>

typedef __attribute__((ext_vector_type(8))) short  bf16x8;
typedef __attribute__((ext_vector_type(4))) float  f32x4;

#define MTPW 4   // tiles per wave in msg_kernel

__device__ __forceinline__ float rcp_(float v){ return __builtin_amdgcn_rcpf(v); }
__device__ __forceinline__ float exp2_(float v){ return __builtin_amdgcn_exp2f(v); }
__device__ __forceinline__ float sigm_(float v){
    return rcp_(1.0f + exp2_(v * -1.442695041f));
}
__device__ __forceinline__ float tanh_(float v){
    float vc = fminf(v, 15.0f);
    float t = exp2_(vc * 2.885390082f);
    return (t - 1.0f) * rcp_(t + 1.0f);
}
__device__ __forceinline__ unsigned pk2(float lo, float hi){
    __hip_bfloat162 h = __float22bfloat162_rn(float2{lo, hi});
    return *(unsigned*)&h;
}
__device__ __forceinline__ float lo2f(unsigned u){ return __uint_as_float(u << 16); }
__device__ __forceinline__ float hi2f(unsigned u){ return __uint_as_float(u & 0xFFFF0000u); }

union U4 { bf16x8 v; unsigned u[4]; };

__device__ __forceinline__ bf16x8 ldw8(const float* __restrict__ p){
    const float4 a = *(const float4*)p;
    const float4 b = *(const float4*)(p + 4);
    U4 r;
    r.u[0] = pk2(a.x, a.y); r.u[1] = pk2(a.z, a.w);
    r.u[2] = pk2(b.x, b.y); r.u[3] = pk2(b.z, b.w);
    return r.v;
}

// [Wih | bias | 0] fragment: k=0..5 features, k=6 bias, k=7 zero; lanes lq>0 zero
__device__ __forceinline__ bf16x8 ldih(const float* __restrict__ wih,
                                       const float* __restrict__ bi,
                                       const float* __restrict__ bh,
                                       int row, int lq){
    U4 r;
    r.u[0] = r.u[1] = r.u[2] = r.u[3] = 0u;
    if (lq == 0) {
        const float* p = wih + row * 6;
        r.u[0] = pk2(p[0], p[1]);
        r.u[1] = pk2(p[2], p[3]);
        r.u[2] = pk2(p[4], p[5]);
        r.u[3] = pk2(bi[row] + bh[row], 0.0f);
    }
    return r.v;
}

// Redistribute per-edge 32-vector from D layout (lane q: positions {4q..4q+3}
// as W0/W1 [lo], {16+4q..16+4q+3} as W2/W3 [hi]) to B-frag/e-major layout
// (lane q: positions {8q..8q+7}). Select lo/hi at the TARGET.
__device__ __forceinline__ void redist(unsigned W0, unsigned W1, unsigned W2, unsigned W3,
                                       int sa, int sb, bool lo, unsigned out[4]){
    const unsigned a0 = (unsigned)__shfl((int)W0, sa, 64);
    const unsigned a1 = (unsigned)__shfl((int)W1, sa, 64);
    const unsigned a2 = (unsigned)__shfl((int)W0, sb, 64);
    const unsigned a3 = (unsigned)__shfl((int)W1, sb, 64);
    const unsigned b0 = (unsigned)__shfl((int)W2, sa, 64);
    const unsigned b1 = (unsigned)__shfl((int)W3, sa, 64);
    const unsigned b2 = (unsigned)__shfl((int)W2, sb, 64);
    const unsigned b3 = (unsigned)__shfl((int)W3, sb, 64);
    out[0] = lo ? a0 : b0;
    out[1] = lo ? a1 : b1;
    out[2] = lo ? a2 : b2;
    out[3] = lo ? a3 : b3;
}

// ---------------- kernel 1: coor = relu(x@W1^T)@W2^T -> bf16 [N,32] ----------------
__global__ __launch_bounds__(256) void coor_kernel(
    const float* __restrict__ x, const float* __restrict__ w1,
    const float* __restrict__ w2, unsigned short* __restrict__ coorb, int N)
{
    __shared__ float sW1[96];
    __shared__ float sW2[1024];
    const int tid = threadIdx.x;
    if (tid < 96) sW1[tid] = w1[tid];
    for (int i = tid; i < 1024; i += 256) sW2[i] = w2[i];
    __syncthreads();
    int n = blockIdx.x * 256 + tid;
    if (n >= N) return;
    const float x0 = x[n*3+0], x1 = x[n*3+1], x2 = x[n*3+2];
    float h[32];
#pragma unroll
    for (int k = 0; k < 32; ++k)
        h[k] = fmaxf(sW1[k*3+0]*x0 + sW1[k*3+1]*x1 + sW1[k*3+2]*x2, 0.0f);
    union { uint4 q[4]; unsigned u[16]; } st;
#pragma unroll
    for (int p = 0; p < 16; ++p) {
        float a0 = 0.f, a1 = 0.f;
#pragma unroll
        for (int k = 0; k < 32; ++k) {
            a0 += sW2[(2*p)  *32 + k] * h[k];
            a1 += sW2[(2*p+1)*32 + k] * h[k];
        }
        st.u[p] = pk2(a0, a1);
    }
    uint4* cp = (uint4*)(coorb + (size_t)n * 32);
#pragma unroll
    for (int w = 0; w < 4; ++w) cp[w] = st.q[w];
}

// ---------------- kernel 2: one-direction LSTM over 16-edge tiles ----------------
// DIR=0: c_fwd -> cbuf (bf16 e-major [E][16] words). DIR=1: c_bwd; read cbuf,
// write tr = 0.5*(cf+cb) in place.
template<int DIR>
__global__ __launch_bounds__(256, 3) void lstm_kernel(
    const float* __restrict__ edge_traj,
    const float* __restrict__ w_ih, const float* __restrict__ w_hh,
    const float* __restrict__ b_ih, const float* __restrict__ b_hh,
    unsigned* __restrict__ cbuf, int E)
{
    const int lane = threadIdx.x & 63;
    const int wid  = threadIdx.x >> 6;
    const int le   = lane & 15;
    const int lq   = lane >> 4;
    const int sa   = ((lq & 1) << 5) + le;
    const int sb   = sa + 16;
    const bool lo  = (lq < 2);
    const f32x4 Z4 = {0.f, 0.f, 0.f, 0.f};

    bf16x8 wh[8], wx[8];
#pragma unroll
    for (int m = 0; m < 8; ++m) {
        const int row = 16*m + le;
        wh[m] = ldw8(w_hh + row*32 + 8*lq);
        wx[m] = ldih(w_ih, b_ih, b_hh, row, lq);
    }

    const long tile = (long)blockIdx.x * 4 + wid;
    const long e0 = tile * 16;
    if (e0 >= E) return;
    const long e_raw = e0 + le;
    const long ec = (e_raw < E) ? e_raw : (E - 1);
    const float* xb = edge_traj + ec * 48;

    U4 hf; hf.u[0] = hf.u[1] = hf.u[2] = hf.u[3] = 0u;
    float c_lo[4] = {0,0,0,0}, c_hi[4] = {0,0,0,0};
#pragma unroll
    for (int t = 0; t < 8; ++t) {
        const int te = DIR ? (7 - t) : t;
        U4 xf; xf.u[0] = xf.u[1] = xf.u[2] = xf.u[3] = 0u;
        if (lq == 0) {
            const float* xp = xb + te * 6;
            const float2 a  = *(const float2*)xp;
            const float2 b2 = *(const float2*)(xp + 2);
            const float2 c2 = *(const float2*)(xp + 4);
            xf.u[0] = pk2(a.x, a.y);
            xf.u[1] = pk2(b2.x, b2.y);
            xf.u[2] = pk2(c2.x, c2.y);
            xf.u[3] = 0x3f80u;              // k=6 -> 1.0 (bias), k=7 -> 0
        }
        f32x4 acc[8];
#pragma unroll
        for (int m = 0; m < 8; ++m)
            acc[m] = __builtin_amdgcn_mfma_f32_16x16x32_bf16(wx[m], xf.v, Z4, 0, 0, 0);
        if (t > 0) {                        // h==0 at t==0: skip the h-MFMAs
#pragma unroll
            for (int m = 0; m < 8; ++m)
                acc[m] = __builtin_amdgcn_mfma_f32_16x16x32_bf16(wh[m], hf.v, acc[m], 0, 0, 0);
        }
        float h_lo[4], h_hi[4];
#pragma unroll
        for (int r = 0; r < 4; ++r) {
            float ig = sigm_(acc[0][r]);
            float fg = sigm_(acc[2][r]);
            float gg = tanh_(acc[4][r]);
            float og = sigm_(acc[6][r]);
            c_lo[r] = fg * c_lo[r] + ig * gg;
            h_lo[r] = og * tanh_(c_lo[r]);
            ig = sigm_(acc[1][r]);
            fg = sigm_(acc[3][r]);
            gg = tanh_(acc[5][r]);
            og = sigm_(acc[7][r]);
            c_hi[r] = fg * c_hi[r] + ig * gg;
            h_hi[r] = og * tanh_(c_hi[r]);
        }
        if (t < 7)
            redist(pk2(h_lo[0], h_lo[1]), pk2(h_lo[2], h_lo[3]),
                   pk2(h_hi[0], h_hi[1]), pk2(h_hi[2], h_hi[3]),
                   sa, sb, lo, hf.u);
    }

    // c -> e-major bf16 (B-frag layout for downstream MFMA)
    U4 cw;
    redist(pk2(c_lo[0], c_lo[1]), pk2(c_lo[2], c_lo[3]),
           pk2(c_hi[0], c_hi[1]), pk2(c_hi[2], c_hi[3]),
           sa, sb, lo, cw.u);
    unsigned* dp = cbuf + (e0 + le) * 16 + lq * 4;
    if (DIR == 0) {
        *(uint4*)dp = *(uint4*)cw.u;
    } else {
        const uint4 f = *(const uint4*)dp;
        uint4 o;
        o.x = pk2(0.5f*(lo2f(f.x)+lo2f(cw.u[0])), 0.5f*(hi2f(f.x)+hi2f(cw.u[0])));
        o.y = pk2(0.5f*(lo2f(f.y)+lo2f(cw.u[1])), 0.5f*(hi2f(f.y)+hi2f(cw.u[1])));
        o.z = pk2(0.5f*(lo2f(f.z)+lo2f(cw.u[2])), 0.5f*(hi2f(f.z)+hi2f(cw.u[2])));
        o.w = pk2(0.5f*(lo2f(f.w)+lo2f(cw.u[3])), 0.5f*(hi2f(f.w)+hi2f(cw.u[3])));
        *(uint4*)dp = o;
    }
}

// ---------------- kernel 3: message MLP + scatter ----------------
__global__ __launch_bounds__(256, 4) void msg_kernel(
    const unsigned* __restrict__ tr,      // [E][16] words, e-major bf16
    const float* __restrict__ nn2_w1, const float* __restrict__ nn2_w2,
    const int* __restrict__ edge_index,
    const unsigned short* __restrict__ coorb,
    float* __restrict__ agg, int E)
{
    const int lane = threadIdx.x & 63;
    const int wid  = threadIdx.x >> 6;
    const int le   = lane & 15;
    const int lq   = lane >> 4;
    const int sa   = ((lq & 1) << 5) + le;
    const int sb   = sa + 16;
    const bool lo  = (lq < 2);
    const f32x4 Z4 = {0.f, 0.f, 0.f, 0.f};

    bf16x8 w1a[2][3], w2a[2];
#pragma unroll
    for (int mm = 0; mm < 2; ++mm) {
        const int row = 16*mm + le;
#pragma unroll
        for (int kc = 0; kc < 3; ++kc)
            w1a[mm][kc] = ldw8(nn2_w1 + row*96 + 32*kc + 8*lq);
        w2a[mm] = ldw8(nn2_w2 + row*32 + 8*lq);
    }

    const long gw = (long)blockIdx.x * 4 + wid;
    for (int it = 0; it < MTPW; ++it) {
        const long tile = gw * MTPW + it;
        const long e0 = tile * 16;
        if (e0 >= E) break;
        const long e_raw = e0 + le;
        const bool valid = e_raw < E;
        const long ec = valid ? e_raw : (E - 1);

        U4 tf;
        *(uint4*)tf.u = *(const uint4*)(tr + ec * 16 + lq * 4);

        const int src = edge_index[ec];
        const int dst = edge_index[E + ec];
        U4 df, sf;
        {
            const uint4 dv = *(const uint4*)(coorb + (size_t)dst*32 + lq*8);
            const uint4 sv = *(const uint4*)(coorb + (size_t)src*32 + lq*8);
            df.u[0]=dv.x; df.u[1]=dv.y; df.u[2]=dv.z; df.u[3]=dv.w;
            sf.u[0]=sv.x; sf.u[1]=sv.y; sf.u[2]=sv.z; sf.u[3]=sv.w;
        }

        f32x4 h1[2];
#pragma unroll
        for (int mm = 0; mm < 2; ++mm) {
            f32x4 a = __builtin_amdgcn_mfma_f32_16x16x32_bf16(w1a[mm][0], df.v, Z4, 0, 0, 0);
            a = __builtin_amdgcn_mfma_f32_16x16x32_bf16(w1a[mm][1], sf.v, a, 0, 0, 0);
            a = __builtin_amdgcn_mfma_f32_16x16x32_bf16(w1a[mm][2], tf.v, a, 0, 0, 0);
            h1[mm] = a;
        }
        U4 gf;
        redist(pk2(fmaxf(h1[0][0],0.f), fmaxf(h1[0][1],0.f)),
               pk2(fmaxf(h1[0][2],0.f), fmaxf(h1[0][3],0.f)),
               pk2(fmaxf(h1[1][0],0.f), fmaxf(h1[1][1],0.f)),
               pk2(fmaxf(h1[1][2],0.f), fmaxf(h1[1][3],0.f)),
               sa, sb, lo, gf.u);

#pragma unroll
        for (int mm = 0; mm < 2; ++mm) {
            const f32x4 o = __builtin_amdgcn_mfma_f32_16x16x32_bf16(w2a[mm], gf.v, Z4, 0, 0, 0);
            if (valid) {
#pragma unroll
                for (int r = 0; r < 4; ++r)
                    atomicAdd(agg + (size_t)dst*32 + (16*mm + 4*lq + r), o[r]);
            }
        }
    }
}

// ---------------- kernel 4: s32[k] = sum_n relu(agg[n]@nn_w1^T)[k] ----------------
__global__ __launch_bounds__(256) void agg_kernel(
    const float* __restrict__ agg, const float* __restrict__ nn_w1,
    float* __restrict__ s32, int N)
{
    __shared__ float sW[1024];
    const int tid = threadIdx.x;
    for (int i = tid; i < 1024; i += 256) sW[i] = nn_w1[i];
    __syncthreads();
    const int n = blockIdx.x*256 + tid;
    float h[32];
    if (n < N) {
        float a[32];
        const float4* ap = (const float4*)(agg + (size_t)n*32);
#pragma unroll
        for (int k4 = 0; k4 < 8; ++k4) {
            const float4 v = ap[k4];
            a[k4*4]=v.x; a[k4*4+1]=v.y; a[k4*4+2]=v.z; a[k4*4+3]=v.w;
        }
#pragma unroll
        for (int jj = 0; jj < 32; ++jj) {
            float acc = 0.f;
#pragma unroll
            for (int k = 0; k < 32; ++k) acc += sW[jj*32+k]*a[k];
            h[jj] = fmaxf(acc, 0.f);
        }
    } else {
#pragma unroll
        for (int jj = 0; jj < 32; ++jj) h[jj] = 0.f;
    }
#pragma unroll
    for (int m = 1; m < 64; m <<= 1) {
#pragma unroll
        for (int k = 0; k < 32; ++k) h[k] += __shfl_xor(h[k], m, 64);
    }
    if ((tid & 63) == 0) {
#pragma unroll
        for (int k = 0; k < 32; ++k) atomicAdd(s32 + k, h[k]);
    }
}

// ---------------- kernel 5: out[o] = nn_w2[o,:] . s32 ----------------
__global__ void final_kernel(const float* __restrict__ nn_w2,
                             const float* __restrict__ s32, float* __restrict__ out)
{
    const int o = threadIdx.x;   // 64
    float acc = 0.f;
#pragma unroll
    for (int k = 0; k < 32; ++k) acc += nn_w2[o*32+k] * s32[k];
    out[o] = acc;
}

extern "C" void kernel_launch(void* const* d_in, const int* in_sizes, int n_in,
                              void* d_out, int out_size, void* d_ws, size_t ws_size,
                              hipStream_t stream)
{
    const float* x         = (const float*)d_in[0];
    const float* edge_traj = (const float*)d_in[1];
    const float* w_ih_f    = (const float*)d_in[2];
    const float* w_hh_f    = (const float*)d_in[3];
    const float* b_ih_f    = (const float*)d_in[4];
    const float* b_hh_f    = (const float*)d_in[5];
    const float* w_ih_b    = (const float*)d_in[6];
    const float* w_hh_b    = (const float*)d_in[7];
    const float* b_ih_b    = (const float*)d_in[8];
    const float* b_hh_b    = (const float*)d_in[9];
    const float* coor_w1   = (const float*)d_in[10];
    const float* coor_w2   = (const float*)d_in[11];
    const float* nn2_w1    = (const float*)d_in[12];
    const float* nn2_w2    = (const float*)d_in[13];
    const float* nn_w1     = (const float*)d_in[14];
    const float* nn_w2     = (const float*)d_in[15];
    const int* edge_index  = (const int*)d_in[16];
    const int N = in_sizes[0] / 3;
    const int E = in_sizes[16] / 2;

    float* agg = (float*)d_ws;                                   // N*32 f32
    float* s32 = agg + (size_t)N * 32;                           // 64 f32
    unsigned short* coorb = (unsigned short*)(s32 + 64);         // N*32 bf16
    unsigned* cbuf = (unsigned*)(coorb + (size_t)N * 32);        // E*16 u32

    (void)hipMemsetAsync(agg, 0, ((size_t)N*32 + 64) * sizeof(float), stream);

    coor_kernel<<<(N + 255)/256, 256, 0, stream>>>(x, coor_w1, coor_w2, coorb, N);

    const long tiles   = ((long)E + 15) / 16;
    const int  lblocks = (int)((tiles + 3) / 4);
    lstm_kernel<0><<<lblocks, 256, 0, stream>>>(edge_traj,
        w_ih_f, w_hh_f, b_ih_f, b_hh_f, cbuf, E);
    lstm_kernel<1><<<lblocks, 256, 0, stream>>>(edge_traj,
        w_ih_b, w_hh_b, b_ih_b, b_hh_b, cbuf, E);

    const int mblocks = (int)((tiles + 4*MTPW - 1) / (4*MTPW));
    msg_kernel<<<mblocks, 256, 0, stream>>>(cbuf, nn2_w1, nn2_w2,
        edge_index, coorb, agg, E);

    agg_kernel<<<(N + 255)/256, 256, 0, stream>>>(agg, nn_w1, s32, N);
    final_kernel<<<1, 64, 0, stream>>>(nn_w2, s32, (float*)d_out);
}

// Round 6
// 1010.889 us; speedup vs baseline: 1.4288x; 1.4288x over previous
//
#include <hip/hip_runtime.h>
#include <hip/hip_bf16.h>

typedef __attribute__((ext_vector_type(8))) short  bf16x8;
typedef __attribute__((ext_vector_type(4))) float  f32x4;

#define MTPW 4   // tiles per wave in msg_kernel

__device__ __forceinline__ float rcp_(float v){ return __builtin_amdgcn_rcpf(v); }
__device__ __forceinline__ float exp2_(float v){ return __builtin_amdgcn_exp2f(v); }
__device__ __forceinline__ float sigm_(float v){
    return rcp_(1.0f + exp2_(v * -1.442695041f));
}
__device__ __forceinline__ float tanh_(float v){
    float vc = fminf(v, 15.0f);
    float t = exp2_(vc * 2.885390082f);
    return (t - 1.0f) * rcp_(t + 1.0f);
}
__device__ __forceinline__ unsigned pk2(float lo, float hi){
    __hip_bfloat162 h = __float22bfloat162_rn(float2{lo, hi});
    return *(unsigned*)&h;
}
__device__ __forceinline__ float lo2f(unsigned u){ return __uint_as_float(u << 16); }
__device__ __forceinline__ float hi2f(unsigned u){ return __uint_as_float(u & 0xFFFF0000u); }

union U4 { bf16x8 v; unsigned u[4]; };

__device__ __forceinline__ bf16x8 ldw8(const float* __restrict__ p){
    const float4 a = *(const float4*)p;
    const float4 b = *(const float4*)(p + 4);
    U4 r;
    r.u[0] = pk2(a.x, a.y); r.u[1] = pk2(a.z, a.w);
    r.u[2] = pk2(b.x, b.y); r.u[3] = pk2(b.z, b.w);
    return r.v;
}

// [Wih | bias | 0] fragment: k=0..5 features, k=6 bias, k=7 zero; lanes lq>0 zero
__device__ __forceinline__ bf16x8 ldih(const float* __restrict__ wih,
                                       const float* __restrict__ bi,
                                       const float* __restrict__ bh,
                                       int row, int lq){
    U4 r;
    r.u[0] = r.u[1] = r.u[2] = r.u[3] = 0u;
    if (lq == 0) {
        const float* p = wih + row * 6;
        r.u[0] = pk2(p[0], p[1]);
        r.u[1] = pk2(p[2], p[3]);
        r.u[2] = pk2(p[4], p[5]);
        r.u[3] = pk2(bi[row] + bh[row], 0.0f);
    }
    return r.v;
}

// Redistribute per-edge 32-vector from D layout (lane q: positions {4q..4q+3}
// as W0/W1 [lo], {16+4q..16+4q+3} as W2/W3 [hi]) to B-frag/e-major layout
// (lane q: positions {8q..8q+7}). Select lo/hi at the TARGET.
__device__ __forceinline__ void redist(unsigned W0, unsigned W1, unsigned W2, unsigned W3,
                                       int sa, int sb, bool lo, unsigned out[4]){
    const unsigned a0 = (unsigned)__shfl((int)W0, sa, 64);
    const unsigned a1 = (unsigned)__shfl((int)W1, sa, 64);
    const unsigned a2 = (unsigned)__shfl((int)W0, sb, 64);
    const unsigned a3 = (unsigned)__shfl((int)W1, sb, 64);
    const unsigned b0 = (unsigned)__shfl((int)W2, sa, 64);
    const unsigned b1 = (unsigned)__shfl((int)W3, sa, 64);
    const unsigned b2 = (unsigned)__shfl((int)W2, sb, 64);
    const unsigned b3 = (unsigned)__shfl((int)W3, sb, 64);
    out[0] = lo ? a0 : b0;
    out[1] = lo ? a1 : b1;
    out[2] = lo ? a2 : b2;
    out[3] = lo ? a3 : b3;
}

// ---------------- kernel 1: coor = relu(x@W1^T)@W2^T -> bf16 [N,32] ----------------
__global__ __launch_bounds__(256) void coor_kernel(
    const float* __restrict__ x, const float* __restrict__ w1,
    const float* __restrict__ w2, unsigned short* __restrict__ coorb, int N)
{
    __shared__ float sW1[96];
    __shared__ float sW2[1024];
    const int tid = threadIdx.x;
    if (tid < 96) sW1[tid] = w1[tid];
    for (int i = tid; i < 1024; i += 256) sW2[i] = w2[i];
    __syncthreads();
    int n = blockIdx.x * 256 + tid;
    if (n >= N) return;
    const float x0 = x[n*3+0], x1 = x[n*3+1], x2 = x[n*3+2];
    float h[32];
#pragma unroll
    for (int k = 0; k < 32; ++k)
        h[k] = fmaxf(sW1[k*3+0]*x0 + sW1[k*3+1]*x1 + sW1[k*3+2]*x2, 0.0f);
    union { uint4 q[4]; unsigned u[16]; } st;
#pragma unroll
    for (int p = 0; p < 16; ++p) {
        float a0 = 0.f, a1 = 0.f;
#pragma unroll
        for (int k = 0; k < 32; ++k) {
            a0 += sW2[(2*p)  *32 + k] * h[k];
            a1 += sW2[(2*p+1)*32 + k] * h[k];
        }
        st.u[p] = pk2(a0, a1);
    }
    uint4* cp = (uint4*)(coorb + (size_t)n * 32);
#pragma unroll
    for (int w = 0; w < 4; ++w) cp[w] = st.q[w];
}

// ---------------- kernel 2: one-direction LSTM over 16-edge tiles ----------------
// DIR=0: c_fwd -> cbuf (bf16 e-major [E][16] words). DIR=1: c_bwd; read cbuf,
// write tr = 0.5*(cf+cb) in place.
template<int DIR>
__global__ __launch_bounds__(256, 3) void lstm_kernel(
    const float* __restrict__ edge_traj,
    const float* __restrict__ w_ih, const float* __restrict__ w_hh,
    const float* __restrict__ b_ih, const float* __restrict__ b_hh,
    unsigned* __restrict__ cbuf, int E)
{
    const int lane = threadIdx.x & 63;
    const int wid  = threadIdx.x >> 6;
    const int le   = lane & 15;
    const int lq   = lane >> 4;
    const int sa   = ((lq & 1) << 5) + le;
    const int sb   = sa + 16;
    const bool lo  = (lq < 2);
    const f32x4 Z4 = {0.f, 0.f, 0.f, 0.f};

    bf16x8 wh[8], wx[8];
#pragma unroll
    for (int m = 0; m < 8; ++m) {
        const int row = 16*m + le;
        wh[m] = ldw8(w_hh + row*32 + 8*lq);
        wx[m] = ldih(w_ih, b_ih, b_hh, row, lq);
    }

    const long tile = (long)blockIdx.x * 4 + wid;
    const long e0 = tile * 16;
    if (e0 >= E) return;
    const long e_raw = e0 + le;
    const long ec = (e_raw < E) ? e_raw : (E - 1);
    const float* xb = edge_traj + ec * 48;

    U4 hf; hf.u[0] = hf.u[1] = hf.u[2] = hf.u[3] = 0u;
    float c_lo[4] = {0,0,0,0}, c_hi[4] = {0,0,0,0};
#pragma unroll
    for (int t = 0; t < 8; ++t) {
        const int te = DIR ? (7 - t) : t;
        U4 xf; xf.u[0] = xf.u[1] = xf.u[2] = xf.u[3] = 0u;
        if (lq == 0) {
            const float* xp = xb + te * 6;
            const float2 a  = *(const float2*)xp;
            const float2 b2 = *(const float2*)(xp + 2);
            const float2 c2 = *(const float2*)(xp + 4);
            xf.u[0] = pk2(a.x, a.y);
            xf.u[1] = pk2(b2.x, b2.y);
            xf.u[2] = pk2(c2.x, c2.y);
            xf.u[3] = 0x3f80u;              // k=6 -> 1.0 (bias), k=7 -> 0
        }
        f32x4 acc[8];
#pragma unroll
        for (int m = 0; m < 8; ++m)
            acc[m] = __builtin_amdgcn_mfma_f32_16x16x32_bf16(wx[m], xf.v, Z4, 0, 0, 0);
        if (t > 0) {                        // h==0 at t==0: skip the h-MFMAs
#pragma unroll
            for (int m = 0; m < 8; ++m)
                acc[m] = __builtin_amdgcn_mfma_f32_16x16x32_bf16(wh[m], hf.v, acc[m], 0, 0, 0);
        }
        float h_lo[4], h_hi[4];
#pragma unroll
        for (int r = 0; r < 4; ++r) {
            float ig = sigm_(acc[0][r]);
            float fg = sigm_(acc[2][r]);
            float gg = tanh_(acc[4][r]);
            float og = sigm_(acc[6][r]);
            c_lo[r] = fg * c_lo[r] + ig * gg;
            h_lo[r] = og * tanh_(c_lo[r]);
            ig = sigm_(acc[1][r]);
            fg = sigm_(acc[3][r]);
            gg = tanh_(acc[5][r]);
            og = sigm_(acc[7][r]);
            c_hi[r] = fg * c_hi[r] + ig * gg;
            h_hi[r] = og * tanh_(c_hi[r]);
        }
        if (t < 7)
            redist(pk2(h_lo[0], h_lo[1]), pk2(h_lo[2], h_lo[3]),
                   pk2(h_hi[0], h_hi[1]), pk2(h_hi[2], h_hi[3]),
                   sa, sb, lo, hf.u);
    }

    // c -> e-major bf16 (B-frag layout for downstream MFMA)
    U4 cw;
    redist(pk2(c_lo[0], c_lo[1]), pk2(c_lo[2], c_lo[3]),
           pk2(c_hi[0], c_hi[1]), pk2(c_hi[2], c_hi[3]),
           sa, sb, lo, cw.u);
    unsigned* dp = cbuf + (e0 + le) * 16 + lq * 4;
    if (DIR == 0) {
        *(uint4*)dp = *(uint4*)cw.u;
    } else {
        const uint4 f = *(const uint4*)dp;
        uint4 o;
        o.x = pk2(0.5f*(lo2f(f.x)+lo2f(cw.u[0])), 0.5f*(hi2f(f.x)+hi2f(cw.u[0])));
        o.y = pk2(0.5f*(lo2f(f.y)+lo2f(cw.u[1])), 0.5f*(hi2f(f.y)+hi2f(cw.u[1])));
        o.z = pk2(0.5f*(lo2f(f.z)+lo2f(cw.u[2])), 0.5f*(hi2f(f.z)+hi2f(cw.u[2])));
        o.w = pk2(0.5f*(lo2f(f.w)+lo2f(cw.u[3])), 0.5f*(hi2f(f.w)+hi2f(cw.u[3])));
        *(uint4*)dp = o;
    }
}

// ---------------- kernel 3: message MLP + scatter ----------------
__global__ __launch_bounds__(256, 4) void msg_kernel(
    const unsigned* __restrict__ tr,      // [E][16] words, e-major bf16
    const float* __restrict__ nn2_w1, const float* __restrict__ nn2_w2,
    const int* __restrict__ edge_index,
    const unsigned short* __restrict__ coorb,
    float* __restrict__ agg, int E)
{
    const int lane = threadIdx.x & 63;
    const int wid  = threadIdx.x >> 6;
    const int le   = lane & 15;
    const int lq   = lane >> 4;
    const int sa   = ((lq & 1) << 5) + le;
    const int sb   = sa + 16;
    const bool lo  = (lq < 2);
    const f32x4 Z4 = {0.f, 0.f, 0.f, 0.f};

    bf16x8 w1a[2][3], w2a[2];
#pragma unroll
    for (int mm = 0; mm < 2; ++mm) {
        const int row = 16*mm + le;
#pragma unroll
        for (int kc = 0; kc < 3; ++kc)
            w1a[mm][kc] = ldw8(nn2_w1 + row*96 + 32*kc + 8*lq);
        w2a[mm] = ldw8(nn2_w2 + row*32 + 8*lq);
    }

    const long gw = (long)blockIdx.x * 4 + wid;
    for (int it = 0; it < MTPW; ++it) {
        const long tile = gw * MTPW + it;
        const long e0 = tile * 16;
        if (e0 >= E) break;
        const long e_raw = e0 + le;
        const bool valid = e_raw < E;
        const long ec = valid ? e_raw : (E - 1);

        U4 tf;
        *(uint4*)tf.u = *(const uint4*)(tr + ec * 16 + lq * 4);

        const int src = edge_index[ec];
        const int dst = edge_index[E + ec];
        U4 df, sf;
        {
            const uint4 dv = *(const uint4*)(coorb + (size_t)dst*32 + lq*8);
            const uint4 sv = *(const uint4*)(coorb + (size_t)src*32 + lq*8);
            df.u[0]=dv.x; df.u[1]=dv.y; df.u[2]=dv.z; df.u[3]=dv.w;
            sf.u[0]=sv.x; sf.u[1]=sv.y; sf.u[2]=sv.z; sf.u[3]=sv.w;
        }

        f32x4 h1[2];
#pragma unroll
        for (int mm = 0; mm < 2; ++mm) {
            f32x4 a = __builtin_amdgcn_mfma_f32_16x16x32_bf16(w1a[mm][0], df.v, Z4, 0, 0, 0);
            a = __builtin_amdgcn_mfma_f32_16x16x32_bf16(w1a[mm][1], sf.v, a, 0, 0, 0);
            a = __builtin_amdgcn_mfma_f32_16x16x32_bf16(w1a[mm][2], tf.v, a, 0, 0, 0);
            h1[mm] = a;
        }
        U4 gf;
        redist(pk2(fmaxf(h1[0][0],0.f), fmaxf(h1[0][1],0.f)),
               pk2(fmaxf(h1[0][2],0.f), fmaxf(h1[0][3],0.f)),
               pk2(fmaxf(h1[1][0],0.f), fmaxf(h1[1][1],0.f)),
               pk2(fmaxf(h1[1][2],0.f), fmaxf(h1[1][3],0.f)),
               sa, sb, lo, gf.u);

#pragma unroll
        for (int mm = 0; mm < 2; ++mm) {
            const f32x4 o = __builtin_amdgcn_mfma_f32_16x16x32_bf16(w2a[mm], gf.v, Z4, 0, 0, 0);
            if (valid) {
#pragma unroll
                for (int r = 0; r < 4; ++r)
                    atomicAdd(agg + (size_t)dst*32 + (16*mm + 4*lq + r), o[r]);
            }
        }
    }
}

// ---------------- kernel 4: partials[b][k] = sum_{n in block b} relu(agg[n]@nn_w1^T)[k] ----------------
// No global atomics: per-wave butterfly -> cross-wave LDS -> one partial row per block.
__global__ __launch_bounds__(256) void agg_kernel(
    const float* __restrict__ agg, const float* __restrict__ nn_w1,
    float* __restrict__ partials, int N)
{
    __shared__ float sW[1024];
    __shared__ float sP[4][32];
    const int tid = threadIdx.x;
    for (int i = tid; i < 1024; i += 256) sW[i] = nn_w1[i];
    __syncthreads();
    const int n = blockIdx.x*256 + tid;
    float h[32];
    if (n < N) {
        float a[32];
        const float4* ap = (const float4*)(agg + (size_t)n*32);
#pragma unroll
        for (int k4 = 0; k4 < 8; ++k4) {
            const float4 v = ap[k4];
            a[k4*4]=v.x; a[k4*4+1]=v.y; a[k4*4+2]=v.z; a[k4*4+3]=v.w;
        }
#pragma unroll
        for (int jj = 0; jj < 32; ++jj) {
            float acc = 0.f;
#pragma unroll
            for (int k = 0; k < 32; ++k) acc += sW[jj*32+k]*a[k];
            h[jj] = fmaxf(acc, 0.f);
        }
    } else {
#pragma unroll
        for (int jj = 0; jj < 32; ++jj) h[jj] = 0.f;
    }
#pragma unroll
    for (int m = 1; m < 64; m <<= 1) {
#pragma unroll
        for (int k = 0; k < 32; ++k) h[k] += __shfl_xor(h[k], m, 64);
    }
    if ((tid & 63) == 0) {
#pragma unroll
        for (int k = 0; k < 32; ++k) sP[tid >> 6][k] = h[k];
    }
    __syncthreads();
    if (tid < 32)
        partials[(size_t)blockIdx.x * 32 + tid]
            = sP[0][tid] + sP[1][tid] + sP[2][tid] + sP[3][tid];
}

// ---------------- kernel 5: s32 = sum(partials); out = nn_w2 @ s32 ----------------
__global__ __launch_bounds__(256) void reduce_kernel(
    const float* __restrict__ partials, const float* __restrict__ nn_w2,
    float* __restrict__ out, int nblk)
{
    __shared__ float sR[8][32];
    __shared__ float sS[32];
    const int tid = threadIdx.x;
    const int col = tid & 31;
    const int row = tid >> 5;          // 8 rows
    float s = 0.f;
    for (int i = row; i < nblk; i += 8) s += partials[(size_t)i*32 + col];
    sR[row][col] = s;
    __syncthreads();
    if (row == 0) {
        float t = 0.f;
#pragma unroll
        for (int r = 0; r < 8; ++r) t += sR[r][col];
        sS[col] = t;
    }
    __syncthreads();
    if (tid < 64) {
        float acc = 0.f;
#pragma unroll
        for (int k = 0; k < 32; ++k) acc += nn_w2[tid*32+k] * sS[k];
        out[tid] = acc;
    }
}

extern "C" void kernel_launch(void* const* d_in, const int* in_sizes, int n_in,
                              void* d_out, int out_size, void* d_ws, size_t ws_size,
                              hipStream_t stream)
{
    const float* x         = (const float*)d_in[0];
    const float* edge_traj = (const float*)d_in[1];
    const float* w_ih_f    = (const float*)d_in[2];
    const float* w_hh_f    = (const float*)d_in[3];
    const float* b_ih_f    = (const float*)d_in[4];
    const float* b_hh_f    = (const float*)d_in[5];
    const float* w_ih_b    = (const float*)d_in[6];
    const float* w_hh_b    = (const float*)d_in[7];
    const float* b_ih_b    = (const float*)d_in[8];
    const float* b_hh_b    = (const float*)d_in[9];
    const float* coor_w1   = (const float*)d_in[10];
    const float* coor_w2   = (const float*)d_in[11];
    const float* nn2_w1    = (const float*)d_in[12];
    const float* nn2_w2    = (const float*)d_in[13];
    const float* nn_w1     = (const float*)d_in[14];
    const float* nn_w2     = (const float*)d_in[15];
    const int* edge_index  = (const int*)d_in[16];
    const int N = in_sizes[0] / 3;
    const int E = in_sizes[16] / 2;
    const int nblk = (N + 255) / 256;

    float* agg = (float*)d_ws;                                   // N*32 f32
    float* partials = agg + (size_t)N * 32;                      // nblk*32 f32
    unsigned short* coorb = (unsigned short*)(partials + (size_t)nblk * 32); // N*32 bf16
    unsigned* cbuf = (unsigned*)(coorb + (size_t)N * 32);        // E*16 u32

    (void)hipMemsetAsync(agg, 0, (size_t)N * 32 * sizeof(float), stream);

    coor_kernel<<<nblk, 256, 0, stream>>>(x, coor_w1, coor_w2, coorb, N);

    const long tiles   = ((long)E + 15) / 16;
    const int  lblocks = (int)((tiles + 3) / 4);
    lstm_kernel<0><<<lblocks, 256, 0, stream>>>(edge_traj,
        w_ih_f, w_hh_f, b_ih_f, b_hh_f, cbuf, E);
    lstm_kernel<1><<<lblocks, 256, 0, stream>>>(edge_traj,
        w_ih_b, w_hh_b, b_ih_b, b_hh_b, cbuf, E);

    const int mblocks = (int)((tiles + 4*MTPW - 1) / (4*MTPW));
    msg_kernel<<<mblocks, 256, 0, stream>>>(cbuf, nn2_w1, nn2_w2,
        edge_index, coorb, agg, E);

    agg_kernel<<<nblk, 256, 0, stream>>>(agg, nn_w1, partials, N);
    reduce_kernel<<<1, 256, 0, stream>>>(partials, nn_w2, (float*)d_out, nblk);
}